// Round 13
// baseline (619.330 us; speedup 1.0000x reference)
//
#include <hip/hip_runtime.h>
#include <hip/hip_bf16.h>

// CustomRNN: h_{t+1} = tanh([x_t | h_t] @ W_ih + b_ih), out = h_final @ W_ho + b_ho
// BATCH=512, SEQ=1024, IN=64, HID=256, CLS=10.
//
// 256 blocks x 512 threads (8 waves, 2/SIMD), TWO batch rows per block,
// 1 block/CU. R13 = R12 + CROSS-STEP PRE-ACCUMULATION: of the 10 k-tiles of
// step t+1, three do NOT depend on foreign h(t+1):
//   - x-tiles 0,1: x(t+1) staged 2 steps ahead -> readable pre-barrier,
//   - own h-tile (k-tile w): written by THIS wave; DS ops are wave-ordered,
//     so it can be read back and MFMA'd before the barrier.
// These 6 MFMAs (into a fresh accumulator set) execute in the tanh/write/
// lgkm-drain shadow at the end of step t. Post-barrier chain = 7 foreign
// k-tiles, reads all issued in one burst at the step top.
// Weight slots are ROTATED per wave at load time (slots 0-6 = chunks
// (w+1..w+7)&7, 7 = own, 8-9 = x) so register arrays stay statically indexed.
// launch_bounds(512,2) = 1 block/CU -> VGPR cap 256; ~170 demand, no spill.
// Carried: register-resident W (pre-scaled 2*log2e), interleaved conflict-
// free LDS [chunk][row][32], A-reads exec-masked to frow<2, raw lgkm-only
// barrier (global x loads stay in flight), balanced x staging.

#define BATCH 512
#define SEQ   1024
#define INP   64
#define HID   256
#define CLS   10
#define NTHREADS 512
#define TSCALE 2.8853900817779268f // 2*log2(e), folded into W_ih/b_ih

typedef short bf16x8 __attribute__((ext_vector_type(8)));
typedef float f32x4  __attribute__((ext_vector_type(4)));

static __device__ __forceinline__ unsigned short f2bf(float f) {
  __hip_bfloat16 h = __float2bfloat16(f);   // RNE
  return *reinterpret_cast<unsigned short*>(&h);
}
static __device__ __forceinline__ float bf2f(unsigned short b) {
  union { unsigned int u; float f; } v; v.u = ((unsigned int)b) << 16;
  return v.f;
}
static __device__ __forceinline__ unsigned int cvt_pk_bf16(float lo, float hi) {
  unsigned int r;
  asm("v_cvt_pk_bf16_f32 %0, %1, %2" : "=v"(r) : "v"(lo), "v"(hi));
  return r;
}
static __device__ __forceinline__ float fast_exp2(float x) {
#if __has_builtin(__builtin_amdgcn_exp2f)
  return __builtin_amdgcn_exp2f(x);
#else
  return __exp2f(x);
#endif
}
static __device__ __forceinline__ float fast_rcp(float x) {
#if __has_builtin(__builtin_amdgcn_rcpf)
  return __builtin_amdgcn_rcpf(x);
#else
  return 1.0f / x;
#endif
}
// pre-activation already scaled by 2*log2(e): tanh(x) = 1 - 2/(1 + exp2(s)).
static __device__ __forceinline__ float tanh_scaled(float s) {
  return 1.0f - 2.0f * fast_rcp(1.0f + fast_exp2(s));
}

#define MFMA16(A, B, C) __builtin_amdgcn_mfma_f32_16x16x32_bf16(A, B, C, 0, 0, 0)

// Drain LDS ops only; in-flight global x loads (vmcnt) stay pending.
#define BARRIER() asm volatile("s_waitcnt lgkmcnt(0)\n\ts_barrier" ::: "memory")

// One scan step. Entering: AI* hold bias + x(T) + own-h(T) contributions
// (pre-accumulated during step T-1). Body: finish 7 foreign k-tiles of h(T),
// tanh -> write own slice of h(T+1), then PRE-ACCUMULATE AO* for step T+1
// (x(T+1) read pre-barrier from sX[NXT]; own h(T+1) slice read back after our
// own write — DS ops are wave-ordered). Stage x(T+2) into sX[CUR]; barrier.
#define STEP(T, CUR, AI0a, AI0b, AI1a, AI1b, AO0a, AO0b, AO1a, AO1b, XR) do {   \
    const int NXT_ = (CUR) ^ 1;                                                 \
    bf16x8 f0 = {}, f1 = {}, f2 = {}, f3 = {}, f4 = {}, f5 = {}, f6 = {};       \
    bf16x8 xf0 = {}, xf1 = {};                                                  \
    if (frow < 2) {  /* burst-issue all reads for this step */                  \
      f0 = *(const bf16x8*)&sH[CUR][(wave + 1) & 7][frow][g8];                  \
      f1 = *(const bf16x8*)&sH[CUR][(wave + 2) & 7][frow][g8];                  \
      f2 = *(const bf16x8*)&sH[CUR][(wave + 3) & 7][frow][g8];                  \
      f3 = *(const bf16x8*)&sH[CUR][(wave + 4) & 7][frow][g8];                  \
      f4 = *(const bf16x8*)&sH[CUR][(wave + 5) & 7][frow][g8];                  \
      f5 = *(const bf16x8*)&sH[CUR][(wave + 6) & 7][frow][g8];                  \
      f6 = *(const bf16x8*)&sH[CUR][(wave + 7) & 7][frow][g8];                  \
      xf0 = *(const bf16x8*)&sX[NXT_][0][frow][g8];                             \
      xf1 = *(const bf16x8*)&sX[NXT_][1][frow][g8];                             \
    }                                                                           \
    AI0a = MFMA16(f0, bwS[0][0], AI0a); AI1a = MFMA16(f0, bwS[0][1], AI1a);     \
    AI0b = MFMA16(f1, bwS[1][0], AI0b); AI1b = MFMA16(f1, bwS[1][1], AI1b);     \
    AI0a = MFMA16(f2, bwS[2][0], AI0a); AI1a = MFMA16(f2, bwS[2][1], AI1a);     \
    AI0b = MFMA16(f3, bwS[3][0], AI0b); AI1b = MFMA16(f3, bwS[3][1], AI1b);     \
    AI0a = MFMA16(f4, bwS[4][0], AI0a); AI1a = MFMA16(f4, bwS[4][1], AI1a);     \
    AI0b = MFMA16(f5, bwS[5][0], AI0b); AI1b = MFMA16(f5, bwS[5][1], AI1b);     \
    AI0a = MFMA16(f6, bwS[6][0], AI0a); AI1a = MFMA16(f6, bwS[6][1], AI1a);     \
    /* D: col=lane&15, row=4g+j -> rows 0,1 live in g==0 lanes, j=0,1 */        \
    float t00 = tanh_scaled(AI0a[0] + AI0b[0]);   /* row0, col 32w+2f   */      \
    float t10 = tanh_scaled(AI1a[0] + AI1b[0]);   /* row0, col 32w+2f+1 */      \
    float t01 = tanh_scaled(AI0a[1] + AI0b[1]);   /* row1, col 32w+2f   */      \
    float t11 = tanh_scaled(AI1a[1] + AI1b[1]);   /* row1, col 32w+2f+1 */      \
    if (g == 0) {                                                               \
      unsigned int* hd_ = (unsigned int*)sH[NXT_];                              \
      hd_[wave * 32 + frow]      = cvt_pk_bf16(t00, t10);   /* row 0 */         \
      hd_[wave * 32 + 16 + frow] = cvt_pk_bf16(t01, t11);   /* row 1 */         \
    }                                                                           \
    /* pre-accumulate step T+1: x-tiles + own h(T+1) slice (read-after-write   \
       within this wave: DS ops complete in order). */                          \
    AO0a = f32x4{bias0, bias0, 0.f, 0.f};                                       \
    AO1a = f32x4{bias1, bias1, 0.f, 0.f};                                       \
    AO0b = f32x4{0.f, 0.f, 0.f, 0.f};                                           \
    AO1b = f32x4{0.f, 0.f, 0.f, 0.f};                                           \
    bf16x8 fown = {};                                                           \
    if (frow < 2) fown = *(const bf16x8*)&sH[NXT_][wave][frow][g8];             \
    AO0a = MFMA16(xf0, bwS[8][0], AO0a); AO1a = MFMA16(xf0, bwS[8][1], AO1a);   \
    AO0b = MFMA16(xf1, bwS[9][0], AO0b); AO1b = MFMA16(xf1, bwS[9][1], AO1b);   \
    AO0a = MFMA16(fown, bwS[7][0], AO0a); AO1a = MFMA16(fown, bwS[7][1], AO1a); \
    /* stage x(T+2) (in XR, loaded 2 steps ago) -> sX[CUR]; XR = x(T+4) */      \
    if (lane < 8) {                                                             \
      ((unsigned int*)sX[CUR])[((scp >> 4) * 2 + srow) * 16 + (scp & 15)]       \
          = cvt_pk_bf16(XR.x, XR.y);                                            \
      int tn_ = (T) + 4; tn_ = tn_ < SEQ ? tn_ : SEQ - 1;                       \
      XR = *(const float2*)&xstage[(size_t)tn_ * INP];                          \
    }                                                                           \
    BARRIER();                                                                  \
  } while (0)

__global__ __launch_bounds__(NTHREADS, 2)
void rnn_scan_kernel(const float* __restrict__ x,
                     const float* __restrict__ W_ih,
                     const float* __restrict__ b_ih,
                     const float* __restrict__ W_ho,
                     const float* __restrict__ b_ho,
                     float* __restrict__ out) {
  // Interleaved layout: [buf][chunk][row][32 elems]; element (r,c) of the
  // logical 2x256 h-panel lives at sH[buf][c>>5][r][c&31]. Masked A-read
  // (8 lanes: g=0..3, frow=0..1) hits bytes chunk*128 + frow*64 + 16g ->
  // dword banks frow*16+4g: 8 distinct banks, conflict-free.
  __shared__ __align__(16) unsigned short sH[2][8][2][32];  // 2 x 1 KB
  __shared__ __align__(16) unsigned short sX[2][2][2][32];  // 2 x 256 B

  const int tid  = threadIdx.x;
  const int lane = tid & 63;
  const int wave = tid >> 6;          // 0..7
  const int b0   = blockIdx.x * 2;    // two batch rows per block

  const int g    = (lane >> 4) & 3;   // k-group within fragment
  const int g8   = g * 8;             // element offset within k-tile chunk
  const int frow = lane & 15;         // A-row (reads) / B,D tile-col

  // ---- Preload W_ih as B-fragments (bf16, pre-scaled by TSCALE), slot-
  // ROTATED per wave: slots 0-6 = foreign h-tiles (chunks (w+1..w+7)&7),
  // slot 7 = own h-tile (chunk w), slots 8,9 = x-tiles. W row of h-chunk c
  // k-element i: INP + c*32 + g*8 + i; x-tile kx: kx*32 + g*8 + i.
  bf16x8 bwS[10][2];
  const int colE = 32 * wave + 2 * frow;
  const float bias0 = b_ih[colE] * TSCALE;
  const float bias1 = b_ih[colE + 1] * TSCALE;
#pragma unroll
  for (int i = 0; i < 10; ++i) {
    int krow0;
    if (i < 7)       krow0 = INP + ((wave + 1 + i) & 7) * 32;
    else if (i == 7) krow0 = INP + wave * 32;
    else             krow0 = (i - 8) * 32;
#pragma unroll
    for (int q = 0; q < 2; ++q) {
      bf16x8 v;
#pragma unroll
      for (int e = 0; e < 8; ++e)
        v[e] = (short)f2bf(W_ih[(size_t)(krow0 + g * 8 + e) * HID + colE + q] * TSCALE);
      bwS[i][q] = v;
    }
  }

  // ---- x staging geometry: wave w lanes 0-7 own slot = 8w + lane
  // (slot -> row = slot>>5, col-pair = slot&31).
  const int slot = wave * 8 + (lane & 7);
  const int srow = slot >> 5, scp = slot & 31;
  const float* xstage = x + (size_t)(b0 + srow) * SEQ * INP + scp * 2;
  float2 xrE = make_float2(0.f, 0.f), xrO = make_float2(0.f, 0.f);

  // ---- Prologue: h(0)=0 in sH[0]; stage x(0)->sX[0], x(1)->sX[1];
  // xrE = x(2), xrO = x(3).
  if (tid < 256) ((unsigned int*)sH[0])[tid] = 0u;
  if (tid < 128) {
    const int tt = tid >> 6;            // 0 or 1
    const int sl = tid & 63;
    const int r = sl >> 5, cp = sl & 31;
    const float2 v = *(const float2*)&x[((size_t)(b0 + r) * SEQ + tt) * INP + cp * 2];
    ((unsigned int*)sX[tt])[((cp >> 4) * 2 + r) * 16 + (cp & 15)]
        = cvt_pk_bf16(v.x, v.y);
  }
  if (lane < 8) {
    xrE = *(const float2*)&xstage[(size_t)2 * INP];
    xrO = *(const float2*)&xstage[(size_t)3 * INP];
  }
  BARRIER();

  // ---- Pre-accumulate step 0 into accE (x(0) from sX[0]; own h(0) = zeros).
  f32x4 aE0a, aE0b, aE1a, aE1b, aO0a, aO0b, aO1a, aO1b;
  {
    bf16x8 xf0 = {}, xf1 = {}, fown = {};
    if (frow < 2) {
      xf0 = *(const bf16x8*)&sX[0][0][frow][g8];
      xf1 = *(const bf16x8*)&sX[0][1][frow][g8];
      fown = *(const bf16x8*)&sH[0][wave][frow][g8];   // zeros
    }
    aE0a = f32x4{bias0, bias0, 0.f, 0.f};
    aE1a = f32x4{bias1, bias1, 0.f, 0.f};
    aE0b = f32x4{0.f, 0.f, 0.f, 0.f};
    aE1b = f32x4{0.f, 0.f, 0.f, 0.f};
    aE0a = MFMA16(xf0, bwS[8][0], aE0a); aE1a = MFMA16(xf0, bwS[8][1], aE1a);
    aE0b = MFMA16(xf1, bwS[9][0], aE0b); aE1b = MFMA16(xf1, bwS[9][1], aE1b);
    aE0a = MFMA16(fown, bwS[7][0], aE0a); aE1a = MFMA16(fown, bwS[7][1], aE1a);
  }

  // ---- Main scan: unroll-2; acc sets and x-prefetch regs swap statically.
#pragma unroll 1
  for (int t = 0; t < SEQ; t += 2) {
    STEP(t,     0, aE0a, aE0b, aE1a, aE1b, aO0a, aO0b, aO1a, aO1b, xrE);
    STEP(t + 1, 1, aO0a, aO0b, aO1a, aO1b, aE0a, aE0b, aE1a, aE1b, xrO);
  }
  // SEQ even -> h_final = h(SEQ) in sH[0]; last pre-acc (aE*) discarded.

  // ---- Head: out[b0+r] = h_final @ W_ho + b_ho (2 rows x 10 cols).
  if (tid < 2 * CLS) {
    const int r = tid / CLS, cl = tid - r * CLS;
    float s = b_ho[cl];
#pragma unroll 8
    for (int k = 0; k < HID; ++k)
      s += bf2f(sH[0][k >> 5][r][k & 31]) * W_ho[(size_t)k * CLS + cl];
    out[(size_t)(b0 + r) * CLS + cl] = s;
  }
}

extern "C" void kernel_launch(void* const* d_in, const int* in_sizes, int n_in,
                              void* d_out, int out_size, void* d_ws, size_t ws_size,
                              hipStream_t stream) {
  const float* x    = (const float*)d_in[0];
  const float* W_ih = (const float*)d_in[1];
  const float* b_ih = (const float*)d_in[2];
  const float* W_ho = (const float*)d_in[3];
  const float* b_ho = (const float*)d_in[4];
  float* out = (float*)d_out;

  rnn_scan_kernel<<<BATCH / 2, NTHREADS, 0, stream>>>(x, W_ih, b_ih, W_ho, b_ho, out);
}